// Round 12
// baseline (106834.021 us; speedup 1.0000x reference)
//
#include <hip/hip_runtime.h>
#include <math.h>
#include <stdint.h>

#define TT 2048
#define BB 64
#define II 256
#define HH 512
#define EHD 128
#define GATEWG 128
#define NWG 132

typedef __attribute__((ext_vector_type(8))) short s16x8;
typedef __attribute__((ext_vector_type(4))) float f32x4;
typedef __attribute__((ext_vector_type(4))) uint32_t u32x4;

#define WAITVM(N) asm volatile("s_waitcnt vmcnt(" #N ")" ::: "memory")
#define VMFENCE() do { asm volatile("" ::: "memory"); __builtin_amdgcn_sched_barrier(0); } while(0)
#define SCHEDFENCE() __builtin_amdgcn_sched_barrier(0)

// ---------------- scalar helpers ----------------
__device__ __forceinline__ float dot4(const float4 a, const float4 b){
    return a.x*b.x + a.y*b.y + a.z*b.z + a.w*b.w;
}
__device__ __forceinline__ float sigm(float x){ return 1.0f/(1.0f+expf(-x)); }
__device__ __forceinline__ float leakyf(float x){ return x > 0.0f ? x : 0.01f*x; }
__device__ __forceinline__ float alphaf(float x){
    float p = 1.0f/(1.0f+expf(-x));
    return p/(1.0f-p);
}
__device__ __forceinline__ f32x4 MFMA(s16x8 a, s16x8 b, f32x4 c){
    return __builtin_amdgcn_mfma_f32_16x16x32_bf16(a, b, c, 0, 0, 0);
}
__device__ __forceinline__ s16x8 as_s16x8(u32x4 v){
    union { u32x4 u; s16x8 s; } x; x.u = v; return x.s;
}

// ---------------- coherent (cross-XCD) access ----------------
__device__ __forceinline__ uint32_t cld_u32(const uint32_t* p){
    return __hip_atomic_load(p, __ATOMIC_RELAXED, __HIP_MEMORY_SCOPE_AGENT);
}
__device__ __forceinline__ void cst_u32(uint32_t* p, uint32_t v){
    __hip_atomic_store(p, v, __ATOMIC_RELAXED, __HIP_MEMORY_SCOPE_AGENT);
}
// wide coherent load: 2x dwordx4 with sc0 sc1 (2 VM ops, 32B)
__device__ __forceinline__ void cld2x4(const void* p, u32x4& a, u32x4& b){
    asm volatile("global_load_dwordx4 %0, %2, off sc0 sc1\n\t"
                 "global_load_dwordx4 %1, %2, off offset:16 sc0 sc1"
                 : "=&v"(a), "=&v"(b) : "v"(p) : "memory");
}
// wide cached load (read-only data)
__device__ __forceinline__ void ld2x4(const void* p, u32x4& a, u32x4& b){
    asm volatile("global_load_dwordx4 %0, %2, off\n\t"
                 "global_load_dwordx4 %1, %2, off offset:16"
                 : "=&v"(a), "=&v"(b) : "v"(p) : "memory");
}
// single cached dwordx4 (1 VM op, 16B)
__device__ __forceinline__ void ld1x4(const void* p, u32x4& a){
    asm volatile("global_load_dwordx4 %0, %1, off"
                 : "=v"(a) : "v"(p) : "memory");
}

// packed bf16 hi/lo pair
__device__ __forceinline__ uint32_t packsplit(float v){
    uint32_t u  = __float_as_uint(v);
    uint32_t hi = u & 0xFFFF0000u;
    float    lo = v - __uint_as_float(hi);
    return hi | (__float_as_uint(lo) >> 16);
}
__device__ __forceinline__ float unpackf(uint32_t w){
    return __uint_as_float(w & 0xFFFF0000u) + __uint_as_float(w << 16);
}

// ---------------- release-flag barrier (R8, proven) ----------------
__device__ __forceinline__ int bar_sum(const int* bar){
    int s = 0;
    #pragma unroll
    for (int i = 0; i < 8; i++)
        s += (int)cld_u32((const uint32_t*)(bar + i*32));
    return s;
}
__device__ __forceinline__ void gbar(int* bar, int epoch){
    asm volatile("s_waitcnt vmcnt(0)" ::: "memory");
    __syncthreads();
    if (threadIdx.x == 0){
        __hip_atomic_fetch_add(bar + (blockIdx.x & 7)*32, 1,
                               __ATOMIC_RELAXED, __HIP_MEMORY_SCOPE_AGENT);
        if (blockIdx.x == 0){
            const int target = NWG * epoch;
            while (bar_sum(bar) < target)
                __builtin_amdgcn_s_sleep(1);
            cst_u32((uint32_t*)(bar + 8*32), (uint32_t)epoch);
        } else {
            while ((int)cld_u32((const uint32_t*)(bar + 8*32)) < epoch)
                __builtin_amdgcn_s_sleep(2);
        }
    }
    __syncthreads();
}
__device__ __forceinline__ void wgbar_lgkm(){
    asm volatile("s_waitcnt lgkmcnt(0)" ::: "memory");
    __builtin_amdgcn_s_barrier();
}

// ---------------- fragment builders ----------------
__device__ __forceinline__ void mk_frag2(u32x4 a, u32x4 b, s16x8* hi, s16x8* lo){
    union { u32x4 u; s16x8 s; } H, L;
    H.u[0] = __builtin_amdgcn_perm(a[1], a[0], 0x07060302u);
    H.u[1] = __builtin_amdgcn_perm(a[3], a[2], 0x07060302u);
    H.u[2] = __builtin_amdgcn_perm(b[1], b[0], 0x07060302u);
    H.u[3] = __builtin_amdgcn_perm(b[3], b[2], 0x07060302u);
    L.u[0] = __builtin_amdgcn_perm(a[1], a[0], 0x05040100u);
    L.u[1] = __builtin_amdgcn_perm(a[3], a[2], 0x05040100u);
    L.u[2] = __builtin_amdgcn_perm(b[1], b[0], 0x05040100u);
    L.u[3] = __builtin_amdgcn_perm(b[3], b[2], 0x05040100u);
    *hi = H.s; *lo = L.s;
}
__device__ __forceinline__ void pack8(const float* f, s16x8* hi, s16x8* lo){
    union { u32x4 u; s16x8 s; } H, L;
    #pragma unroll
    for (int i = 0; i < 4; i++){
        float a = f[2*i], b = f[2*i+1];
        uint32_t ua = __float_as_uint(a), ub = __float_as_uint(b);
        uint32_t ha = ua & 0xFFFF0000u, hb = ub & 0xFFFF0000u;
        H.u[i] = (ua >> 16) | hb;
        float la = a - __uint_as_float(ha), lb = b - __uint_as_float(hb);
        L.u[i] = (__float_as_uint(la) >> 16) | (__float_as_uint(lb) & 0xFFFF0000u);
    }
    *hi = H.s; *lo = L.s;
}

// ---------------- fp32 encoder block (PROLOGUE ONLY) ----------------
__device__ void enc_h_block(int e, const uint32_t* __restrict__ hsrc,
                            uint32_t* __restrict__ htil,
                            const float* __restrict__ w1, const float* __restrict__ b1,
                            const float* __restrict__ w2, const float* __restrict__ b2,
                            const float* __restrict__ w3, const float* __restrict__ b3,
                            float* smem)
{
    float* hlds = smem;
    float* t1   = smem + 4*516;
    float* t2   = t1 + 4*132;
    const int tid = threadIdx.x;
    const int r0 = e * 4;
    #pragma unroll
    for (int i = 0; i < 8; i++){
        int el = tid + i*256;
        int rr = el >> 9, k = el & 511;
        hlds[rr*516 + k] = unpackf(cld_u32(hsrc + (r0+rr)*HH + k));
    }
    __syncthreads();
    const int cc = tid & 63;
    const int rr = (tid >> 6) & 3;
    for (int cb = 0; cb < 2; cb++){
        int c = cc + cb*64;
        const float* wr = w1 + c*HH;
        const float* xr = hlds + rr*516;
        float a0 = b1[c], a1 = 0.f;
        #pragma unroll 8
        for (int k = 0; k < HH; k += 8){
            a0 += dot4(*(const float4*)(xr+k),   *(const float4*)(wr+k));
            a1 += dot4(*(const float4*)(xr+k+4), *(const float4*)(wr+k+4));
        }
        t1[rr*132 + c] = leakyf(a0 + a1);
    }
    __syncthreads();
    for (int cb = 0; cb < 2; cb++){
        int c = cc + cb*64;
        const float* wr = w2 + c*EHD;
        const float* xr = t1 + rr*132;
        float a0 = b2[c], a1 = 0.f;
        #pragma unroll 4
        for (int k = 0; k < EHD; k += 8){
            a0 += dot4(*(const float4*)(xr+k),   *(const float4*)(wr+k));
            a1 += dot4(*(const float4*)(xr+k+4), *(const float4*)(wr+k+4));
        }
        t2[rr*132 + c] = leakyf(a0 + a1);
    }
    __syncthreads();
    for (int cb = 0; cb < 8; cb++){
        int c = cc + cb*64;
        const float* wr = w3 + c*EHD;
        const float* xr = t2 + rr*132;
        float a0 = b3[c], a1 = 0.f;
        #pragma unroll 4
        for (int k = 0; k < EHD; k += 8){
            a0 += dot4(*(const float4*)(xr+k),   *(const float4*)(wr+k));
            a1 += dot4(*(const float4*)(xr+k+4), *(const float4*)(wr+k+4));
        }
        float a = alphaf(a0 + a1);
        cst_u32(htil + (r0+rr)*HH + c, packsplit(hlds[rr*516 + c] * a));
    }
    __syncthreads();
}

__global__ __launch_bounds__(256) void enc_only_kernel(
    const uint32_t* __restrict__ hsrc, uint32_t* __restrict__ htil,
    const float* __restrict__ w1, const float* __restrict__ b1,
    const float* __restrict__ w2, const float* __restrict__ b2,
    const float* __restrict__ w3, const float* __restrict__ b3)
{
    __shared__ float smem[3120];
    enc_h_block(blockIdx.x, hsrc, htil, w1, b1, w2, b2, w3, b3, smem);
}

// ---------------- x' = input * alpha_y(input): packed, [T][B][I] ----------------
__global__ __launch_bounds__(256) void ency_kernel(
    const float* __restrict__ xin, uint32_t* __restrict__ xprime,
    const float* __restrict__ w1, const float* __restrict__ b1,
    const float* __restrict__ w2, const float* __restrict__ b2,
    const float* __restrict__ w3, const float* __restrict__ b3)
{
    __shared__ float t1[32*128];
    __shared__ float t2[32*128];
    const long m0 = (long)blockIdx.x * 32;
    const int tid = threadIdx.x;
    const int cc = tid & 63;
    const int rr = tid >> 6;
    for (int cb = 0; cb < 2; cb++){
        int c = cc + cb*64;
        const float* wr = w1 + c*II;
        for (int q = 0; q < 8; q++){
            int r = rr*8 + q;
            const float* xr = xin + (m0 + r)*II;
            float a0 = b1[c], a1 = 0.f;
            #pragma unroll 8
            for (int k = 0; k < II; k += 8){
                a0 += dot4(*(const float4*)(xr+k),   *(const float4*)(wr+k));
                a1 += dot4(*(const float4*)(xr+k+4), *(const float4*)(wr+k+4));
            }
            t1[r*128 + c] = leakyf(a0 + a1);
        }
    }
    __syncthreads();
    for (int cb = 0; cb < 2; cb++){
        int c = cc + cb*64;
        const float* wr = w2 + c*EHD;
        for (int q = 0; q < 8; q++){
            int r = rr*8 + q;
            const float* xr = t1 + r*128;
            float a0 = b2[c], a1 = 0.f;
            #pragma unroll 4
            for (int k = 0; k < EHD; k += 8){
                a0 += dot4(*(const float4*)(xr+k),   *(const float4*)(wr+k));
                a1 += dot4(*(const float4*)(xr+k+4), *(const float4*)(wr+k+4));
            }
            t2[r*128 + c] = leakyf(a0 + a1);
        }
    }
    __syncthreads();
    for (int cb = 0; cb < 4; cb++){
        int c = cc + cb*64;
        const float* wr = w3 + c*EHD;
        for (int q = 0; q < 8; q++){
            int r = rr*8 + q;
            const float* xr = t2 + r*128;
            float a0 = b3[c], a1 = 0.f;
            #pragma unroll 4
            for (int k = 0; k < EHD; k += 8){
                a0 += dot4(*(const float4*)(xr+k),   *(const float4*)(wr+k));
                a1 += dot4(*(const float4*)(xr+k+4), *(const float4*)(wr+k+4));
            }
            float a = alphaf(a0 + a1);
            long m = m0 + r;                       // m = b*TT + t
            long b = m >> 11, t = m & 2047;
            xprime[((long)t*BB + b)*II + c] = packsplit(xin[m*II + c] * a);
        }
    }
}

// ---------------- gate weight packing ----------------
__global__ __launch_bounds__(64) void prep_pack_kernel(
    const float* __restrict__ Wih0, const float* __restrict__ Whh0,
    const float* __restrict__ Wih1, const float* __restrict__ Whh1,
    ushort* __restrict__ wpack)
{
    const int b = blockIdx.x;          // 128*56
    const int lane = threadIdx.x;
    const int g4 = b / 56, kts = b % 56;
    const int layer = (kts >= 24) ? 1 : 0;
    const int kt = layer ? (kts - 24) : kts;
    const int c = lane & 15;
    const int gate = c >> 2, uu = c & 3;
    const int n = gate*512 + g4*4 + uu;
    const int k = kt*32 + (lane >> 4)*8;
    const float* src;
    if (!layer){
        if (k < 256) src = Wih0 + (long)n*II + k;
        else         src = Whh0 + (long)n*HH + (k - 256);
    } else {
        if (k < 512) src = Wih1 + (long)n*HH + k;
        else         src = Whh1 + (long)n*HH + (k - 512);
    }
    ushort hi[8], lo[8];
    #pragma unroll
    for (int j = 0; j < 8; j++){
        float v = src[j];
        uint32_t u = __float_as_uint(v);
        hi[j] = (ushort)(u >> 16);
        float hf = __uint_as_float(u & 0xFFFF0000u);
        lo[j] = (ushort)(__float_as_uint(v - hf) >> 16);
    }
    long bhi = ((long)g4*7168 + kts*64 + lane) * 8;
    long blo = bhi + (long)3584*8;
    #pragma unroll
    for (int j = 0; j < 8; j++){ wpack[bhi + j] = hi[j]; wpack[blo + j] = lo[j]; }
}

// ---------------- encoder weight packing ----------------
__global__ __launch_bounds__(64) void enc_pack_kernel(
    const float* __restrict__ w1, const float* __restrict__ w2,
    const float* __restrict__ w3, ushort* __restrict__ epack)
{
    const int f = blockIdx.x;      // 0..287
    const int lane = threadIdx.x;
    const int c = lane & 15, kq = lane >> 4;
    const float* src;
    if (f < 128){
        int nt = f >> 4, kt = f & 15;
        src = w1 + (long)(nt*16 + c)*HH + kt*32 + kq*8;
    } else if (f < 160){
        int q = f - 128; int nt = q >> 2, kt = q & 3;
        src = w2 + (long)(nt*16 + c)*EHD + kt*32 + kq*8;
    } else {
        int q = f - 160; int nt = q >> 2, kt = q & 3;
        src = w3 + (long)(nt*16 + c)*EHD + kt*32 + kq*8;
    }
    long off = ((long)f*64 + lane)*8;
    #pragma unroll
    for (int j = 0; j < 8; j++){
        float v = src[j];
        uint32_t u = __float_as_uint(v);
        epack[off + j] = (ushort)(u >> 16);
        float hf = __uint_as_float(u & 0xFFFF0000u);
        epack[off + 147456 + j] = (ushort)(__float_as_uint(v - hf) >> 16);
    }
}

// ---------------- init ----------------
__global__ __launch_bounds__(256) void init_state_kernel(
    const float* __restrict__ h0, uint32_t* __restrict__ hpack, int* __restrict__ bar)
{
    int i = blockIdx.x*256 + threadIdx.x;
    hpack[i] = packsplit(h0[i]);
    if (i < 320) bar[i] = 0;
}

// ---------------- gate phase ----------------
// 128 wgs x 4 cols. 8 waves: rt = wv>>1 (16-row tile), kh = wv&1 (k-half).
// B (hi+lo) fully LDS-resident (loaded once). A in registers, 2 waits/phase.
template<int PHASE>
__device__ __forceinline__ void gate_issueA(int ktg, int t, int brow, int kq,
    const uint32_t* __restrict__ xp, const uint32_t* __restrict__ h0p,
    const uint32_t* __restrict__ htilp, u32x4* d)
{
    if (PHASE == 0){
        if (ktg < 8){
            const uint32_t* p = xp + ((long)t*BB + brow)*II + ktg*32 + kq*8;
            ld2x4(p, d[0], d[1]);
        } else {
            const uint32_t* p = htilp + (long)brow*HH + (ktg-8)*32 + kq*8;
            cld2x4(p, d[0], d[1]);
        }
    } else {
        const uint32_t* p = (ktg < 16)
            ? h0p   + (long)brow*HH + ktg*32      + kq*8
            : htilp + (long)brow*HH + (ktg-16)*32 + kq*8;
        cld2x4(p, d[0], d[1]);
    }
}

template<int PHASE>
__device__ __forceinline__ void gate_phase(
    int t, int tid,
    const s16x8* __restrict__ whl, const s16x8* __restrict__ wlo,
    float* __restrict__ glds,
    const uint32_t* __restrict__ xp,
    const uint32_t* __restrict__ h0p,
    const uint32_t* __restrict__ htilp,
    const float* bsum, uint32_t* __restrict__ hdst,
    int jcol, float* creg, float* hreg, float* __restrict__ yout)
{
    const int lane = tid & 63;
    const int wv   = tid >> 6;               // 0..7
    const int rt   = wv >> 1, kh = wv & 1;
    const int brow = rt*16 + (lane & 15);
    const int kq   = lane >> 4;
    constexpr int KTW = PHASE ? 16 : 12;     // kts per k-half
    constexpr int C1  = KTW - 8;             // kts in chunk 1
    constexpr int KT0 = PHASE ? 24 : 0;      // weight kt base (layer offset)
    const int kt0 = kh * KTW;

    u32x4 d0[16], d1[16];
    #pragma unroll
    for (int j = 0; j < 8; j++)
        gate_issueA<PHASE>(kt0 + j, t, brow, kq, xp, h0p, htilp, &d0[j*2]);
    VMFENCE();
    #pragma unroll
    for (int j = 0; j < C1; j++)
        gate_issueA<PHASE>(kt0 + 8 + j, t, brow, kq, xp, h0p, htilp, &d1[j*2]);
    VMFENCE();

    f32x4 a1 = {0,0,0,0}, a2 = {0,0,0,0};
    // chunk0 = 16 VM ops, chunk1 = 2*C1 ops. Retire chunk0:
    if (PHASE) { WAITVM(16); } else { WAITVM(8); }
    SCHEDFENCE();
    #pragma unroll
    for (int j = 0; j < 8; j++){
        const int wkt = KT0 + kt0 + j;
        s16x8 ah, al; mk_frag2(d0[j*2], d0[j*2+1], &ah, &al);
        s16x8 B1 = whl[wkt*64 + lane];
        s16x8 B2 = wlo[wkt*64 + lane];
        a1 = MFMA(ah, B1, a1);
        a2 = MFMA(al, B1, a2);
        a2 = MFMA(ah, B2, a2);
    }
    WAITVM(0);
    SCHEDFENCE();
    #pragma unroll
    for (int j = 0; j < C1; j++){
        const int wkt = KT0 + kt0 + 8 + j;
        s16x8 ah, al; mk_frag2(d1[j*2], d1[j*2+1], &ah, &al);
        s16x8 B1 = whl[wkt*64 + lane];
        s16x8 B2 = wlo[wkt*64 + lane];
        a1 = MFMA(ah, B1, a1);
        a2 = MFMA(al, B1, a2);
        a2 = MFMA(ah, B2, a2);
    }
    // partial-C exchange: glds[kh*64 + row][17]
    {
        f32x4 caf = a1 + a2;
        const int r0 = kh*64 + rt*16 + (lane>>4)*4;
        const int c16 = lane & 15;
        #pragma unroll
        for (int i = 0; i < 4; i++)
            glds[(r0+i)*17 + c16] = caf[i];
    }
    wgbar_lgkm();
    if (tid < 256){
        const int b = tid >> 2, uu = tid & 3;
        float gi = glds[b*17 + 0  + uu] + glds[(64+b)*17 + 0  + uu] + bsum[0];
        float gf = glds[b*17 + 4  + uu] + glds[(64+b)*17 + 4  + uu] + bsum[1];
        float gg = glds[b*17 + 8  + uu] + glds[(64+b)*17 + 8  + uu] + bsum[2];
        float go = glds[b*17 + 12 + uu] + glds[(64+b)*17 + 12 + uu] + bsum[3];
        float cn = sigm(gf)*(*creg) + sigm(gi)*tanhf(gg);
        float hn = sigm(go)*tanhf(cn);
        *creg = cn; *hreg = hn;
        cst_u32(hdst + b*HH + jcol, packsplit(hn));
        if (yout) yout[((long)b*TT + t)*HH + jcol] = hn;
    }
}

// ---------------- encoder helpers ----------------
// L1 weight chunk c (4 kts x {hi,lo} = 8 VM ops) for wave's NT=wv
__device__ __forceinline__ void enc_l1_issue(int c, int wv, int lane,
    const char* __restrict__ epb, u32x4* buf)
{
    #pragma unroll
    for (int j = 0; j < 4; j++){
        const int kt = c*4 + j;
        ld1x4(epb + (long)(wv*16 + kt)*1024 + lane*16, buf[j*2]);
        ld1x4(epb + (long)(288 + wv*16 + kt)*1024 + lane*16, buf[j*2+1]);
    }
}
__device__ __forceinline__ void enc_l1_mfma(int c, int c16, int kq,
    const uint32_t* __restrict__ hlds, const u32x4* wc, f32x4& p1, f32x4& p2)
{
    #pragma unroll
    for (int j = 0; j < 4; j++){
        const int ktg = c*4 + j;
        const uint32_t* aq = hlds + c16*516 + ktg*32 + kq*8;
        u32x4 qa = *(const u32x4*)aq;
        u32x4 qb = *((const u32x4*)aq + 1);
        s16x8 ah, al; mk_frag2(qa, qb, &ah, &al);
        p1 = MFMA(ah, as_s16x8(wc[j*2]),   p1);
        p2 = MFMA(al, as_s16x8(wc[j*2]),   p2);
        p2 = MFMA(ah, as_s16x8(wc[j*2+1]), p2);
    }
}
// L3 weight chunk q (NT = wv*4+q; 4 kts x {hi,lo} = 8 VM ops)
__device__ __forceinline__ void enc_l3_issue(int q, int wv, int lane,
    const char* __restrict__ epb, u32x4* buf)
{
    #pragma unroll
    for (int kt = 0; kt < 4; kt++){
        const int f = 160 + (wv*4 + q)*4 + kt;
        ld1x4(epb + (long)f*1024 + lane*16, buf[kt*2]);
        ld1x4(epb + (long)(288 + f)*1024 + lane*16, buf[kt*2+1]);
    }
}
__device__ __forceinline__ void enc_l3_block(int q, int wv, int c16, int kq, int r0,
    const u32x4* wc, const s16x8* a3h, const s16x8* a3l,
    const float* b3v, const uint32_t* __restrict__ hlds, uint32_t* __restrict__ htil)
{
    f32x4 s1 = {0,0,0,0}, s2 = {0,0,0,0};
    #pragma unroll
    for (int kt = 0; kt < 4; kt++){
        s1 = MFMA(a3h[kt], as_s16x8(wc[kt*2]),   s1);
        s2 = MFMA(a3l[kt], as_s16x8(wc[kt*2]),   s2);
        s2 = MFMA(a3h[kt], as_s16x8(wc[kt*2+1]), s2);
    }
    f32x4 cc = s1 + s2;
    const int n = wv*64 + q*16 + c16;
    #pragma unroll
    for (int i = 0; i < 4; i++){
        const int row = kq*4 + i;
        float a  = alphaf(cc[i] + b3v[q]);
        float hv = unpackf(hlds[row*516 + n]);
        cst_u32(htil + (long)(r0+row)*HH + n, packsplit(hv * a));
    }
}

// ---------------- encoder phase: 16 rows, 8 waves split n ----------------
__device__ void enc_phase(
    int e, const uint32_t* __restrict__ hsrc, uint32_t* __restrict__ htil,
    const char* __restrict__ epb,
    float b1v, float b2v, const float* b3v,
    uint32_t* __restrict__ hlds, float* __restrict__ t1, float* __restrict__ t2)
{
    const int tid = threadIdx.x;
    const int lane = tid & 63, wv = tid >> 6;     // 0..7
    const int c16 = lane & 15, kq = lane >> 4;
    const int r0 = e * 16;

    // ---- A stage: wave wv loads rows 2wv, 2wv+1 (coherent): 4 VM ops ----
    u32x4 ar[2][2];
    #pragma unroll
    for (int rr = 0; rr < 2; rr++){
        const uint32_t* p = hsrc + (long)(r0 + 2*wv + rr)*HH + lane*8;
        cld2x4(p, ar[rr][0], ar[rr][1]);
    }
    VMFENCE();
    // ---- L2 weights (NT=wv): 8 ops ----
    u32x4 w2r[8];
    #pragma unroll
    for (int kt = 0; kt < 4; kt++){
        ld1x4(epb + (long)(128 + wv*4 + kt)*1024 + lane*16, w2r[kt*2]);
        ld1x4(epb + (long)(288 + 128 + wv*4 + kt)*1024 + lane*16, w2r[kt*2+1]);
    }
    VMFENCE();
    // ---- L1 chunks c0 -> wA, c1 -> wB (8 ops each) ----
    u32x4 wA[8], wB[8], wC[8];
    enc_l1_issue(0, wv, lane, epb, wA); VMFENCE();
    enc_l1_issue(1, wv, lane, epb, wB); VMFENCE();
    // outstanding: A(4), w2r(8), c0(8), c1(8) = 28
    WAITVM(24);                 // retire A
    SCHEDFENCE();
    #pragma unroll
    for (int rr = 0; rr < 2; rr++){
        uint32_t* q = hlds + (2*wv+rr)*516 + lane*8;
        *(u32x4*)q       = ar[rr][0];
        *((u32x4*)q + 1) = ar[rr][1];
    }
    wgbar_lgkm();               // hlds ready

    // ---- layer 1: 16 kts, 4 chunks, 3-buffer rotation ----
    f32x4 p1 = {0,0,0,0}, p2 = {0,0,0,0};
    WAITVM(8);  SCHEDFENCE();                       // retires w2r + c0 (c1 left)
    enc_l1_issue(2, wv, lane, epb, wC); VMFENCE();  // outstanding c1,c2
    enc_l1_mfma(0, c16, kq, hlds, wA, p1, p2);
    WAITVM(8);  SCHEDFENCE();                       // retires c1 (c2 left)
    enc_l1_issue(3, wv, lane, epb, wA); VMFENCE();  // outstanding c2,c3
    enc_l1_mfma(1, c16, kq, hlds, wB, p1, p2);
    WAITVM(8);  SCHEDFENCE();                       // retires c2 (c3 left)
    enc_l1_mfma(2, c16, kq, hlds, wC, p1, p2);
    WAITVM(0);  SCHEDFENCE();                       // retires c3
    enc_l1_mfma(3, c16, kq, hlds, wA, p1, p2);
    {
        f32x4 cc = p1 + p2;
        const int n = wv*16 + c16;
        #pragma unroll
        for (int i = 0; i < 4; i++)
            t1[(kq*4+i)*132 + n] = leakyf(cc[i] + b1v);
    }
    // issue L3 chunks q0 -> wX, q1 -> wY
    u32x4 wX[8], wY[8], wZ[8];
    enc_l3_issue(0, wv, lane, epb, wX); VMFENCE();
    enc_l3_issue(1, wv, lane, epb, wY); VMFENCE();
    wgbar_lgkm();               // t1 ready

    // ---- layer 2: 4 kts (w2r regs valid since layer-1 first wait) ----
    f32x4 q1 = {0,0,0,0}, q2 = {0,0,0,0};
    s16x8 a2h[4], a2l[4];
    #pragma unroll
    for (int kt = 0; kt < 4; kt++)
        pack8(t1 + c16*132 + kt*32 + kq*8, &a2h[kt], &a2l[kt]);
    #pragma unroll
    for (int kt = 0; kt < 4; kt++){
        q1 = MFMA(a2h[kt], as_s16x8(w2r[kt*2]),   q1);
        q2 = MFMA(a2l[kt], as_s16x8(w2r[kt*2]),   q2);
        q2 = MFMA(a2h[kt], as_s16x8(w2r[kt*2+1]), q2);
    }
    {
        f32x4 cc = q1 + q2;
        const int n = wv*16 + c16;
        #pragma unroll
        for (int i = 0; i < 4; i++)
            t2[(kq*4+i)*132 + n] = leakyf(cc[i] + b2v);
    }
    enc_l3_issue(2, wv, lane, epb, wZ); VMFENCE();  // outstanding q0,q1,q2 = 24
    wgbar_lgkm();               // t2 ready

    // ---- layer 3: 4 NT blocks, 3-buffer rotation ----
    s16x8 a3h[4], a3l[4];
    #pragma unroll
    for (int kt = 0; kt < 4; kt++)
        pack8(t2 + c16*132 + kt*32 + kq*8, &a3h[kt], &a3l[kt]);
    WAITVM(16); SCHEDFENCE();                       // retires q0
    enc_l3_block(0, wv, c16, kq, r0, wX, a3h, a3l, b3v, hlds, htil);
    enc_l3_issue(3, wv, lane, epb, wX); VMFENCE();  // outstanding q1,q2,q3
    WAITVM(16); SCHEDFENCE();                       // retires q1
    enc_l3_block(1, wv, c16, kq, r0, wY, a3h, a3l, b3v, hlds, htil);
    WAITVM(8);  SCHEDFENCE();                       // retires q2
    enc_l3_block(2, wv, c16, kq, r0, wZ, a3h, a3l, b3v, hlds, htil);
    WAITVM(0);  SCHEDFENCE();                       // retires q3
    enc_l3_block(3, wv, c16, kq, r0, wX, a3h, a3l, b3v, hlds, htil);
}

// ---------------- persistent kernel ----------------
// wgs 0..127: gates (4 cols each). wgs 128..131: encoders (16 rows each).
__global__ __launch_bounds__(512, 2) void persistent_kernel(
    const uint32_t* __restrict__ xp,
    uint32_t* __restrict__ hpack,
    const ushort* __restrict__ wpack,
    const ushort* __restrict__ epack,
    const float* __restrict__ c0in,
    const float* __restrict__ bih0, const float* __restrict__ bhh0,
    const float* __restrict__ bih1, const float* __restrict__ bhh1,
    const float* __restrict__ ehb1, const float* __restrict__ ehb2,
    const float* __restrict__ ehb3,
    float* __restrict__ out, int* __restrict__ bar)
{
    extern __shared__ char smem_raw[];
    const int wg = blockIdx.x, tid = threadIdx.x;
    uint32_t* h0p = hpack;
    uint32_t* h1p = hpack + 32768;
    uint32_t* ht0 = hpack + 65536;
    uint32_t* ht1 = hpack + 98304;

    if (wg >= GATEWG){
        // -------- encoder wg --------
        uint32_t* hlds = (uint32_t*)smem_raw;            // [16][516] u32
        float* t1 = (float*)(smem_raw + 33024);          // [16][132]
        float* t2 = t1 + 16*132;
        const int e = wg - GATEWG;                       // 0..3
        const char* epb = (const char*)epack;
        const int lane = tid & 63, wv = tid >> 6, c16 = lane & 15;
        float b1v = ehb1[wv*16 + c16];
        float b2v = ehb2[wv*16 + c16];
        float b3v[4];
        #pragma unroll
        for (int q = 0; q < 4; q++) b3v[q] = ehb3[wv*64 + q*16 + c16];
        WAITVM(0);
        __syncthreads();
        for (int t = 0; t < TT; t++){
            enc_phase(e, h1p, ht1, epb, b1v, b2v, b3v, hlds, t1, t2);
            gbar(bar, 2*t+1);
            enc_phase(e, h0p, ht0, epb, b1v, b2v, b3v, hlds, t1, t2);
            gbar(bar, 2*t+2);
        }
        return;
    }
    // -------- gate wg: 4 gate-columns, B weights fully LDS-resident --------
    s16x8* whl  = (s16x8*)smem_raw;                      // 3584 frags (hi)
    s16x8* wlo  = whl + 3584;                            // 3584 frags (lo)
    float* glds = (float*)(whl + 7168);                  // [128][17] floats
    const int g4 = wg;
    {
        const s16x8* wp = (const s16x8*)wpack + (long)g4*7168;
        for (int i = tid; i < 7168; i += 512) whl[i] = wp[i];
    }
    float bsum0[4] = {0,0,0,0}, bsum1[4] = {0,0,0,0};
    float c0reg = 0.f, c1reg = 0.f, h0reg = 0.f, h1reg = 0.f;
    int jcol = 0;
    if (tid < 256){
        const int b = tid >> 2, uu = tid & 3;
        jcol = g4*4 + uu;
        #pragma unroll
        for (int q = 0; q < 4; q++){
            int n = q*512 + jcol;
            bsum0[q] = bih0[n] + bhh0[n];
            bsum1[q] = bih1[n] + bhh1[n];
        }
        c0reg = c0in[b*HH + jcol];
        c1reg = c0in[32768 + b*HH + jcol];
    }
    WAITVM(0);
    __syncthreads();

    for (int t = 0; t < TT; t++){
        gate_phase<0>(t, tid, whl, wlo, glds, xp, h0p, ht0,
                      bsum0, h0p, jcol, &c0reg, &h0reg, nullptr);
        gbar(bar, 2*t+1);
        gate_phase<1>(t, tid, whl, wlo, glds, xp, h0p, ht1,
                      bsum1, h1p, jcol, &c1reg, &h1reg, out);
        gbar(bar, 2*t+2);
    }
    if (tid < 256){
        const int b = tid >> 2;
        const long base = (long)BB*TT*HH;
        out[base +                 b*HH + jcol] = h0reg;
        out[base + 32768         + b*HH + jcol] = h1reg;
        out[base + 65536         + b*HH + jcol] = c0reg;
        out[base + 65536 + 32768 + b*HH + jcol] = c1reg;
    }
}

// ---------------- launch ----------------
extern "C" void kernel_launch(void* const* d_in, const int* in_sizes, int n_in,
                              void* d_out, int out_size, void* d_ws, size_t ws_size,
                              hipStream_t stream)
{
    const float* input = (const float*)d_in[0];
    const float* h0in  = (const float*)d_in[1];
    const float* c0in  = (const float*)d_in[2];
    const float* Wih0  = (const float*)d_in[3];
    const float* Whh0  = (const float*)d_in[4];
    const float* bih0  = (const float*)d_in[5];
    const float* bhh0  = (const float*)d_in[6];
    const float* Wih1  = (const float*)d_in[7];
    const float* Whh1  = (const float*)d_in[8];
    const float* bih1  = (const float*)d_in[9];
    const float* bhh1  = (const float*)d_in[10];
    const float* eyw1  = (const float*)d_in[11];
    const float* eyb1  = (const float*)d_in[12];
    const float* eyw2  = (const float*)d_in[13];
    const float* eyb2  = (const float*)d_in[14];
    const float* eyw3  = (const float*)d_in[15];
    const float* eyb3  = (const float*)d_in[16];
    const float* ehw1  = (const float*)d_in[17];
    const float* ehb1  = (const float*)d_in[18];
    const float* ehw2  = (const float*)d_in[19];
    const float* ehb2  = (const float*)d_in[20];
    const float* ehw3  = (const float*)d_in[21];
    const float* ehb3  = (const float*)d_in[22];

    float* out = (float*)d_out;
    float* ws  = (float*)d_ws;

    uint32_t* xprime = (uint32_t*)ws;                  // [T][B][I] packed
    uint32_t* hpack  = (uint32_t*)(ws + 33554432);     // h0,h1,ht0,ht1
    int*      bar    = (int*)(ws + 33685504);          // 8 arrival lines + release
    ushort*   wpack  = (ushort*)(ws + 33751104);       // 14,680,064 B
    ushort*   epack  = (ushort*)(ws + 37421120);       // 589,824 B

    hipFuncSetAttribute((const void*)persistent_kernel,
                        hipFuncAttributeMaxDynamicSharedMemorySize, 131072);

    init_state_kernel<<<256, 256, 0, stream>>>(h0in, hpack, bar);
    prep_pack_kernel<<<128*56, 64, 0, stream>>>(Wih0, Whh0, Wih1, Whh1, wpack);
    enc_pack_kernel<<<288, 64, 0, stream>>>(ehw1, ehw2, ehw3, epack);
    ency_kernel<<<4096, 256, 0, stream>>>(input, xprime,
                                          eyw1, eyb1, eyw2, eyb2, eyw3, eyb3);
    enc_only_kernel<<<16, 256, 0, stream>>>(hpack, hpack + 65536,
                                            ehw1, ehb1, ehw2, ehb2, ehw3, ehb3);
    persistent_kernel<<<NWG, 512, 123392, stream>>>(
        xprime, hpack, wpack, epack, c0in,
        bih0, bhh0, bih1, bhh1,
        ehb1, ehb2, ehb3,
        out, bar);
}